// Round 11
// baseline (2608.140 us; speedup 1.0000x reference)
//
#include <hip/hip_runtime.h>

#define NB 32
#define NN 2048
#define ND 64
#define ROWS 16
#define NBLK (NB * NN / ROWS)   // 4096 blocks

// LDS map (bytes): S[16][2048] fp16 @0 (row stride 4096, byte ^= (row&7)<<4)
//                  rowsum partials 8w x 16r f32 @65536; kseg aux @66048
#define LDS_PART 65536
#define LDS_AUX  66048
#define LDS_TOTAL 70144

typedef _Float16 half8 __attribute__((ext_vector_type(8)));
typedef float f32x4 __attribute__((ext_vector_type(4)));
typedef int i32x4 __attribute__((ext_vector_type(4)));

union H4 { uint2 u; _Float16 h[4]; };

__device__ __forceinline__ f32x4 mfma16(half8 a, half8 b, f32x4 c) {
    return __builtin_amdgcn_mfma_f32_16x16x32_f16(a, b, c, 0, 0, 0);
}
#define SB() __builtin_amdgcn_sched_barrier(0)
// raw barrier: LDS-ordering only; global stores stay in flight (no vmcnt drain)
#define LBAR() { asm volatile("s_waitcnt lgkmcnt(0)" ::: "memory"); \
                 __builtin_amdgcn_s_barrier(); \
                 __builtin_amdgcn_sched_barrier(0); }

// ---- pre-pass: f32 -> fp16 elementwise ----
__global__ __launch_bounds__(256) void cvt_f32_f16_k(const float* __restrict__ src,
                                                     _Float16* __restrict__ dst) {
    int i = blockIdx.x * 256 + threadIdx.x;
    const f32x4* s = (const f32x4*)src;
    f32x4 a = s[2 * i], b = s[2 * i + 1];
    half8 h;
    h[0] = (_Float16)a[0]; h[1] = (_Float16)a[1]; h[2] = (_Float16)a[2]; h[3] = (_Float16)a[3];
    h[4] = (_Float16)b[0]; h[5] = (_Float16)b[1]; h[6] = (_Float16)b[2]; h[7] = (_Float16)b[3];
    ((half8*)dst)[i] = h;
}

// ---- pre-pass: V[b][k][d] f32 -> Vt[b][d][k] fp16 ----
__global__ __launch_bounds__(256) void transpose_v_k(const float* __restrict__ v,
                                                     _Float16* __restrict__ vt) {
    __shared__ float tile[64][65];
    int b = blockIdx.x >> 5;
    int k0 = (blockIdx.x & 31) * 64;
    int t = threadIdx.x;
    {
        int dc = t & 15, kr = t >> 4;
        const f32x4* vp = (const f32x4*)(v + ((size_t)(b * NN + k0) * ND));
        #pragma unroll
        for (int i = 0; i < 4; ++i) {
            int kk = kr + i * 16;
            f32x4 x = vp[kk * 16 + dc];
            tile[kk][dc * 4 + 0] = x[0]; tile[kk][dc * 4 + 1] = x[1];
            tile[kk][dc * 4 + 2] = x[2]; tile[kk][dc * 4 + 3] = x[3];
        }
    }
    __syncthreads();
    {
        int d = t >> 2, ks = (t & 3) * 16;
        union { _Float16 hh[16]; uint4 u4[2]; } pk;
        #pragma unroll
        for (int j = 0; j < 16; ++j) pk.hh[j] = (_Float16)tile[ks + j][d];
        uint4* op = (uint4*)(vt + ((size_t)(b * ND + d) * NN + k0 + ks));
        op[0] = pk.u4[0]; op[1] = pk.u4[1];
    }
}

// ---- pre-pass: pack mask int32 -> 1 bit, in phase-1 consumption order ----
__global__ __launch_bounds__(256) void mask_pack_k(const int* __restrict__ mask,
                                                   unsigned long long* __restrict__ pm) {
    size_t gid = (size_t)blockIdx.x * 256 + threadIdx.x;
    size_t row = gid >> 5;
    int w = ((int)gid >> 2) & 7, lg = (int)gid & 3;
    const i32x4* mp = (const i32x4*)(mask + row * NN + w * 16 + lg * 4);
    unsigned long long bits = 0ull;
    #pragma unroll
    for (int i = 0; i < 16; i += 4) {
        i32x4 m0 = __builtin_nontemporal_load(mp + (size_t)(i + 0) * 32);
        i32x4 m1 = __builtin_nontemporal_load(mp + (size_t)(i + 1) * 32);
        i32x4 m2 = __builtin_nontemporal_load(mp + (size_t)(i + 2) * 32);
        i32x4 m3 = __builtin_nontemporal_load(mp + (size_t)(i + 3) * 32);
        unsigned b0 = (m0[0] > 0 ? 1u : 0u) | (m0[1] > 0 ? 2u : 0u) | (m0[2] > 0 ? 4u : 0u) | (m0[3] > 0 ? 8u : 0u);
        unsigned b1 = (m1[0] > 0 ? 1u : 0u) | (m1[1] > 0 ? 2u : 0u) | (m1[2] > 0 ? 4u : 0u) | (m1[3] > 0 ? 8u : 0u);
        unsigned b2 = (m2[0] > 0 ? 1u : 0u) | (m2[1] > 0 ? 2u : 0u) | (m2[2] > 0 ? 4u : 0u) | (m2[3] > 0 ? 8u : 0u);
        unsigned b3 = (m3[0] > 0 ? 1u : 0u) | (m3[1] > 0 ? 2u : 0u) | (m3[2] > 0 ? 4u : 0u) | (m3[3] > 0 ? 8u : 0u);
        bits |= (unsigned long long)(b0 | (b1 << 4) | (b2 << 8) | (b3 << 12)) << (i * 4);
    }
    pm[gid] = bits;
}

// ================= main kernel (template-ablated) =================
#define LDK(S, base) { \
    const _Float16* kk_ = kp + (size_t)(base) * (128 * ND); \
    S##0a = *(const half8*)(kk_);                S##0b = *(const half8*)(kk_ + 32); \
    S##1a = *(const half8*)(kk_ + 128 * ND);     S##1b = *(const half8*)(kk_ + 128 * ND + 32); \
    S##2a = *(const half8*)(kk_ + 2 * 128 * ND); S##2b = *(const half8*)(kk_ + 2 * 128 * ND + 32); \
    S##3a = *(const half8*)(kk_ + 3 * 128 * ND); S##3b = *(const half8*)(kk_ + 3 * 128 * ND + 32); }

#define CMP1(i, ka_, kb_) { \
    f32x4 acc = {0.f, 0.f, 0.f, 0.f}; \
    acc = mfma16(ka_, qf0, acc); \
    acc = mfma16(kb_, qf1, acc); \
    unsigned mb = (unsigned)(pmask >> ((i) * 4)) & 15u; \
    float e0 = (mb & 1u) ? __expf(acc[0] * 0.125f) : 0.f; \
    float e1 = (mb & 2u) ? __expf(acc[1] * 0.125f) : 0.f; \
    float e2 = (mb & 4u) ? __expf(acc[2] * 0.125f) : 0.f; \
    float e3 = (mb & 8u) ? __expf(acc[3] * 0.125f) : 0.f; \
    rsum += (e0 + e1) + (e2 + e3); \
    H4 y_; y_.h[0] = (_Float16)e0; y_.h[1] = (_Float16)e1; \
    y_.h[2] = (_Float16)e2; y_.h[3] = (_Float16)e3; \
    *(uint2*)(srow + ((((w * 16 + (i) * 128) + lg * 4) * 2) ^ sw)) = y_.u; }

#define CMP4(S, c) { CMP1((c)*4 + 0, S##0a, S##0b) CMP1((c)*4 + 1, S##1a, S##1b) \
                     CMP1((c)*4 + 2, S##2a, S##2b) CMP1((c)*4 + 3, S##3a, S##3b) }

#define LDV(S, base) { \
    const _Float16* vv_ = vp + (size_t)(kseg * 32 + (base)) * 32; \
    S##0 = *(const half8*)(vv_);       S##1 = *(const half8*)(vv_ + 32); \
    S##2 = *(const half8*)(vv_ + 64);  S##3 = *(const half8*)(vv_ + 96); \
    S##4 = *(const half8*)(vv_ + 128); S##5 = *(const half8*)(vv_ + 160); \
    S##6 = *(const half8*)(vv_ + 192); S##7 = *(const half8*)(vv_ + 224); }

#define PV1(ks_, vb_) { \
    half8 pa_ = *(const half8*)(pbase + ((((ks_) * 64) + lg * 16) ^ sw)); \
    o = mfma16(pa_, vb_, o); }

#define PV8(S, base) { PV1(kseg*32 + (base) + 0, S##0) PV1(kseg*32 + (base) + 1, S##1) \
                       PV1(kseg*32 + (base) + 2, S##2) PV1(kseg*32 + (base) + 3, S##3) \
                       PV1(kseg*32 + (base) + 4, S##4) PV1(kseg*32 + (base) + 5, S##5) \
                       PV1(kseg*32 + (base) + 6, S##6) PV1(kseg*32 + (base) + 7, S##7) }

#define NRM(jj) { \
    int colb_ = g * 8 + (jj) * 256; \
    H4 x_; x_.u = *(const uint2*)(s2 + (colb_ ^ sw2)); \
    f32x4 av_; \
    av_[0] = (float)x_.h[0] * linv; av_[1] = (float)x_.h[1] * linv; \
    av_[2] = (float)x_.h[2] * linv; av_[3] = (float)x_.h[3] * linv; \
    __builtin_nontemporal_store(av_, (f32x4*)(arow + (colb_ >> 1))); }

// VAR: 0 = full, 1 = phase1 only, 2 = phase1+PV+out, 3 = phase1+attn-store
template<int VAR, int REP>
__global__ __launch_bounds__(512, 4) void attn_main_k(
        const _Float16* __restrict__ qh, const _Float16* __restrict__ kh,
        const _Float16* __restrict__ vtp, const unsigned long long* __restrict__ pm,
        float* __restrict__ outp, float* __restrict__ attnp) {
    extern __shared__ char smem[];
    constexpr bool DO_PV  = (VAR == 0 || VAR == 2);
    constexpr bool DO_AST = (VAR == 0 || VAR == 3);

    int bid = blockIdx.x;
    int lin0 = (bid & 7) * (NBLK / 8) + (bid >> 3);   // XCD swizzle, bijective

    int t = threadIdx.x;
    int w = t >> 6, l = t & 63;
    int l15 = l & 15, lg = l >> 4;
    int sw = (l15 & 7) << 4;
    char* srow = smem + l15 * 4096;
    float* part = (float*)(smem + LDS_PART);

    for (int rp = REP - 1; rp >= 0; --rp) {
        if (rp != REP - 1) LBAR();            // protect S/part from previous rep readers
        int lin = lin0 ^ rp;                   // different tile per rep (no cross-rep CSE);
        int b  = lin >> 7;                     // rp==0 last -> own tile -> correct final state
        int q0 = (lin & 127) * ROWS;

        const _Float16* qb = qh + ((size_t)(b * NN + q0 + l15) * ND) + lg * 8;
        half8 qf0 = *(const half8*)(qb);
        half8 qf1 = *(const half8*)(qb + 32);
        unsigned long long pmask = pm[((size_t)(b * NN + q0 + l15) * 8 + w) * 4 + lg];
        const _Float16* kp = kh + (size_t)b * NN * ND + (size_t)(w * 16 + l15) * ND + lg * 8;

        // ---- Phase 1: fused QK^T + maskbits + exp + rowsum ----
        half8 A0a, A0b, A1a, A1b, A2a, A2b, A3a, A3b;
        half8 B0a, B0b, B1a, B1b, B2a, B2b, B3a, B3b;
        float rsum = 0.f;
        LDK(A, 0)  SB();
        LDK(B, 4)  SB();
        CMP4(A, 0) SB();
        LDK(A, 8)  SB();
        CMP4(B, 1) SB();
        LDK(B, 12) SB();
        CMP4(A, 2) SB();
        CMP4(B, 3)

        rsum += __shfl_xor(rsum, 16);
        rsum += __shfl_xor(rsum, 32);
        if (l < 16) part[w * 16 + l] = rsum;
        LBAR();

        if constexpr (VAR == 1) {
            // probe store keeps phase-1 dataflow live; overwritten by VAR0 later
            if (l < 16) outp[(size_t)lin * 128 + w * 16 + l] = rsum;
        }

        if constexpr (DO_PV) {
            // ---- PV (kseg split) + out store ----
            int ct = w & 3, kseg = w >> 2;
            const _Float16* vp = vtp + (size_t)(b * ND + ct * 16 + l15) * NN + lg * 8;
            char* pbase = smem + l15 * 4096;
            f32x4 o = {0.f, 0.f, 0.f, 0.f};
            half8 V0, V1, V2, V3, V4, V5, V6, V7;
            half8 W0, W1, W2, W3, W4, W5, W6, W7;
            LDV(V, 0)   SB();
            LDV(W, 8)   SB();
            PV8(V, 0)   SB();
            LDV(V, 16)  SB();
            PV8(W, 8)   SB();
            LDV(W, 24)  SB();
            PV8(V, 16)  SB();
            PV8(W, 24)

            if (kseg) *(f32x4*)(smem + LDS_AUX + ((size_t)((w - 4) * 64 + l)) * 16) = o;
            LBAR();
            if (!kseg) {
                f32x4 o2 = *(const f32x4*)(smem + LDS_AUX + ((size_t)(w * 64 + l)) * 16);
                o += o2;
                float* ob = outp + ((size_t)(b * NN + q0 + lg * 4)) * ND + ct * 16 + l15;
                #pragma unroll
                for (int rr = 0; rr < 4; ++rr) {
                    int qr = lg * 4 + rr;
                    float s8 = 0.f;
                    #pragma unroll
                    for (int pw = 0; pw < 8; ++pw) s8 += part[pw * 16 + qr];
                    __builtin_nontemporal_store(o[rr] / (s8 + 1e-37f), ob + (size_t)rr * ND);
                }
            }
        }

        if constexpr (DO_AST) {
            // ---- normalize + attn f32 store, all 8 waves ----
            int r = t >> 5, g = t & 31;          // 2 rows/wave, 32 threads/row
            float su = 0.f;
            #pragma unroll
            for (int pw = 0; pw < 8; ++pw) su += part[pw * 16 + r];
            float linv = 1.0f / (su + 1e-37f);   // all-masked row -> attn = 0 (no NaN)
            char* s2 = smem + r * 4096;
            int sw2 = (r & 7) << 4;
            float* arow = attnp + ((size_t)(b * NN + q0 + r)) * NN;
            NRM(0)  NRM(1)  NRM(2)  NRM(3)
            NRM(4)  NRM(5)  NRM(6)  NRM(7)
            NRM(8)  NRM(9)  NRM(10) NRM(11)
            NRM(12) NRM(13) NRM(14) NRM(15)
        }
    }
}

extern "C" void kernel_launch(void* const* d_in, const int* in_sizes, int n_in,
                              void* d_out, int out_size, void* d_ws, size_t ws_size,
                              hipStream_t stream) {
    const float* q = (const float*)d_in[0];
    const float* k = (const float*)d_in[1];
    const float* v = (const float*)d_in[2];
    const int* mask = (const int*)d_in[3];
    float* outp  = (float*)d_out;
    float* attnp = outp + (size_t)NB * NN * ND;

    // ws: qh 8MB | kh 8MB | vt 8MB | pm 16.8MB
    _Float16* qh = (_Float16*)d_ws;
    _Float16* kh = qh + (size_t)NB * NN * ND;
    _Float16* vth = kh + (size_t)NB * NN * ND;
    unsigned long long* pm = (unsigned long long*)(vth + (size_t)NB * NN * ND);

    cvt_f32_f16_k<<<2048, 256, 0, stream>>>(q, qh);
    cvt_f32_f16_k<<<2048, 256, 0, stream>>>(k, kh);
    transpose_v_k<<<1024, 256, 0, stream>>>(v, vth);
    mask_pack_k<<<8192, 256, 0, stream>>>(mask, pm);

    // ---- ablation probes (outputs overwritten by the full variant below) ----
    attn_main_k<1, 4><<<NBLK, 512, LDS_TOTAL, stream>>>(qh, kh, vth, pm, outp, attnp);
    attn_main_k<2, 3><<<NBLK, 512, LDS_TOTAL, stream>>>(qh, kh, vth, pm, outp, attnp);
    attn_main_k<3, 3><<<NBLK, 512, LDS_TOTAL, stream>>>(qh, kh, vth, pm, outp, attnp);
    // ---- full variant LAST: produces the final correct outputs ----
    attn_main_k<0, 2><<<NBLK, 512, LDS_TOTAL, stream>>>(qh, kh, vth, pm, outp, attnp);
}

// Round 12
// 375.877 us; speedup vs baseline: 6.9388x; 6.9388x over previous
//
#include <hip/hip_runtime.h>

#define NB 32
#define NN 2048
#define ND 64
#define ROWS 16
#define NBLK (NB * NN / ROWS)   // 4096 blocks

// LDS map (bytes): S[16][2048] fp16 @0 (row stride 4096, byte ^= (row&7)<<4)
//                  rowsum partials 8w x 16r f32 @65536; kseg aux @66048
#define LDS_PART 65536
#define LDS_AUX  66048
#define LDS_TOTAL 70144

typedef _Float16 half8 __attribute__((ext_vector_type(8)));
typedef float f32x4 __attribute__((ext_vector_type(4)));
typedef int i32x4 __attribute__((ext_vector_type(4)));

union H4 { uint2 u; _Float16 h[4]; };

__device__ __forceinline__ f32x4 mfma16(half8 a, half8 b, f32x4 c) {
    return __builtin_amdgcn_mfma_f32_16x16x32_f16(a, b, c, 0, 0, 0);
}
#define SB() __builtin_amdgcn_sched_barrier(0)
// counted vmem wait + sched fence (rule #18: fence AFTER the waitcnt)
#define WAITV(n) { asm volatile("s_waitcnt vmcnt(" #n ")" ::: "memory"); SB(); }
// raw barrier: LDS-ordering only; global stores stay in flight (no vmcnt drain)
#define LBAR() { asm volatile("s_waitcnt lgkmcnt(0)" ::: "memory"); \
                 __builtin_amdgcn_s_barrier(); \
                 __builtin_amdgcn_sched_barrier(0); }
#define PIN(x) asm volatile("" : "+v"(x))

// ---- pre-pass: f32 -> fp16 elementwise ----
__global__ __launch_bounds__(256) void cvt_f32_f16_k(const float* __restrict__ src,
                                                     _Float16* __restrict__ dst) {
    int i = blockIdx.x * 256 + threadIdx.x;
    const f32x4* s = (const f32x4*)src;
    f32x4 a = s[2 * i], b = s[2 * i + 1];
    half8 h;
    h[0] = (_Float16)a[0]; h[1] = (_Float16)a[1]; h[2] = (_Float16)a[2]; h[3] = (_Float16)a[3];
    h[4] = (_Float16)b[0]; h[5] = (_Float16)b[1]; h[6] = (_Float16)b[2]; h[7] = (_Float16)b[3];
    ((half8*)dst)[i] = h;
}

// ---- pre-pass: V[b][k][d] f32 -> Vt[b][d][k] fp16 ----
__global__ __launch_bounds__(256) void transpose_v_k(const float* __restrict__ v,
                                                     _Float16* __restrict__ vt) {
    __shared__ float tile[64][65];
    int b = blockIdx.x >> 5;
    int k0 = (blockIdx.x & 31) * 64;
    int t = threadIdx.x;
    {
        int dc = t & 15, kr = t >> 4;
        const f32x4* vp = (const f32x4*)(v + ((size_t)(b * NN + k0) * ND));
        #pragma unroll
        for (int i = 0; i < 4; ++i) {
            int kk = kr + i * 16;
            f32x4 x = vp[kk * 16 + dc];
            tile[kk][dc * 4 + 0] = x[0]; tile[kk][dc * 4 + 1] = x[1];
            tile[kk][dc * 4 + 2] = x[2]; tile[kk][dc * 4 + 3] = x[3];
        }
    }
    __syncthreads();
    {
        int d = t >> 2, ks = (t & 3) * 16;
        union { _Float16 hh[16]; uint4 u4[2]; } pk;
        #pragma unroll
        for (int j = 0; j < 16; ++j) pk.hh[j] = (_Float16)tile[ks + j][d];
        uint4* op = (uint4*)(vt + ((size_t)(b * ND + d) * NN + k0 + ks));
        op[0] = pk.u4[0]; op[1] = pk.u4[1];
    }
}

// ---- pre-pass: pack mask int32 -> 1 bit, in phase-1 consumption order ----
__global__ __launch_bounds__(256) void mask_pack_k(const int* __restrict__ mask,
                                                   unsigned long long* __restrict__ pm) {
    size_t gid = (size_t)blockIdx.x * 256 + threadIdx.x;
    size_t row = gid >> 5;
    int w = ((int)gid >> 2) & 7, lg = (int)gid & 3;
    const i32x4* mp = (const i32x4*)(mask + row * NN + w * 16 + lg * 4);
    unsigned long long bits = 0ull;
    #pragma unroll
    for (int i = 0; i < 16; i += 4) {
        i32x4 m0 = __builtin_nontemporal_load(mp + (size_t)(i + 0) * 32);
        i32x4 m1 = __builtin_nontemporal_load(mp + (size_t)(i + 1) * 32);
        i32x4 m2 = __builtin_nontemporal_load(mp + (size_t)(i + 2) * 32);
        i32x4 m3 = __builtin_nontemporal_load(mp + (size_t)(i + 3) * 32);
        unsigned b0 = (m0[0] > 0 ? 1u : 0u) | (m0[1] > 0 ? 2u : 0u) | (m0[2] > 0 ? 4u : 0u) | (m0[3] > 0 ? 8u : 0u);
        unsigned b1 = (m1[0] > 0 ? 1u : 0u) | (m1[1] > 0 ? 2u : 0u) | (m1[2] > 0 ? 4u : 0u) | (m1[3] > 0 ? 8u : 0u);
        unsigned b2 = (m2[0] > 0 ? 1u : 0u) | (m2[1] > 0 ? 2u : 0u) | (m2[2] > 0 ? 4u : 0u) | (m2[3] > 0 ? 8u : 0u);
        unsigned b3 = (m3[0] > 0 ? 1u : 0u) | (m3[1] > 0 ? 2u : 0u) | (m3[2] > 0 ? 4u : 0u) | (m3[3] > 0 ? 8u : 0u);
        bits |= (unsigned long long)(b0 | (b1 << 4) | (b2 << 8) | (b3 << 12)) << (i * 4);
    }
    pm[gid] = bits;
}

// ================= main kernel =================
// Issue one K chunk = 4 key tiles = 8 x 16B asm loads (un-sinkable, stay in order)
#define ISSUEK(S, base) { \
    const char* kc_ = (const char*)kp + (size_t)(base) * 16384; \
    asm volatile("global_load_dwordx4 %0, %2, off\n\t" \
                 "global_load_dwordx4 %1, %2, off offset:64" \
                 : "=&v"(S##0a), "=&v"(S##0b) : "v"(kc_) : "memory"); \
    asm volatile("global_load_dwordx4 %0, %2, off\n\t" \
                 "global_load_dwordx4 %1, %2, off offset:64" \
                 : "=&v"(S##1a), "=&v"(S##1b) : "v"(kc_ + 16384) : "memory"); \
    asm volatile("global_load_dwordx4 %0, %2, off\n\t" \
                 "global_load_dwordx4 %1, %2, off offset:64" \
                 : "=&v"(S##2a), "=&v"(S##2b) : "v"(kc_ + 32768) : "memory"); \
    asm volatile("global_load_dwordx4 %0, %2, off\n\t" \
                 "global_load_dwordx4 %1, %2, off offset:64" \
                 : "=&v"(S##3a), "=&v"(S##3b) : "v"(kc_ + 49152) : "memory"); }

#define CMP1(i, ua_, ub_) { \
    half8 kaa_ = __builtin_bit_cast(half8, ua_); \
    half8 kbb_ = __builtin_bit_cast(half8, ub_); \
    f32x4 acc = {0.f, 0.f, 0.f, 0.f}; \
    acc = mfma16(kaa_, qf0, acc); \
    acc = mfma16(kbb_, qf1, acc); \
    unsigned mb = (unsigned)(pmask >> ((i) * 4)) & 15u; \
    float e0 = (mb & 1u) ? __expf(acc[0] * 0.125f) : 0.f; \
    float e1 = (mb & 2u) ? __expf(acc[1] * 0.125f) : 0.f; \
    float e2 = (mb & 4u) ? __expf(acc[2] * 0.125f) : 0.f; \
    float e3 = (mb & 8u) ? __expf(acc[3] * 0.125f) : 0.f; \
    rsum += (e0 + e1) + (e2 + e3); \
    H4 y_; y_.h[0] = (_Float16)e0; y_.h[1] = (_Float16)e1; \
    y_.h[2] = (_Float16)e2; y_.h[3] = (_Float16)e3; \
    *(uint2*)(srow + ((((w * 16 + (i) * 128) + lg * 4) * 2) ^ sw)) = y_.u; }

#define CMP4(S, c) { CMP1((c)*4 + 0, S##0a, S##0b) CMP1((c)*4 + 1, S##1a, S##1b) \
                     CMP1((c)*4 + 2, S##2a, S##2b) CMP1((c)*4 + 3, S##3a, S##3b) }

// Issue one V chunk = 8 x 16B from one base (offsets 0..448)
#define ISSUEV(S, base) { \
    const char* vc_ = (const char*)(vp + (size_t)(kseg * 32 + (base)) * 32); \
    asm volatile("global_load_dwordx4 %0, %8, off\n\t" \
                 "global_load_dwordx4 %1, %8, off offset:64\n\t" \
                 "global_load_dwordx4 %2, %8, off offset:128\n\t" \
                 "global_load_dwordx4 %3, %8, off offset:192\n\t" \
                 "global_load_dwordx4 %4, %8, off offset:256\n\t" \
                 "global_load_dwordx4 %5, %8, off offset:320\n\t" \
                 "global_load_dwordx4 %6, %8, off offset:384\n\t" \
                 "global_load_dwordx4 %7, %8, off offset:448" \
                 : "=&v"(S##0), "=&v"(S##1), "=&v"(S##2), "=&v"(S##3), \
                   "=&v"(S##4), "=&v"(S##5), "=&v"(S##6), "=&v"(S##7) \
                 : "v"(vc_) : "memory"); }

#define PV1(ks_, ub_) { \
    half8 pa_ = *(const half8*)(pbase + ((((ks_) * 64) + lg * 16) ^ sw)); \
    o = mfma16(pa_, __builtin_bit_cast(half8, ub_), o); }

#define PV8(S, base) { PV1(kseg*32 + (base) + 0, S##0) PV1(kseg*32 + (base) + 1, S##1) \
                       PV1(kseg*32 + (base) + 2, S##2) PV1(kseg*32 + (base) + 3, S##3) \
                       PV1(kseg*32 + (base) + 4, S##4) PV1(kseg*32 + (base) + 5, S##5) \
                       PV1(kseg*32 + (base) + 6, S##6) PV1(kseg*32 + (base) + 7, S##7) }

// dense attn store: 32 lanes x f32x4 -> 512 B/instr, nontemporal (full sectors)
#define NRM(jj) { \
    int colb_ = g * 8 + (jj) * 256; \
    H4 x_; x_.u = *(const uint2*)(s2 + (colb_ ^ sw2)); \
    f32x4 av_; \
    av_[0] = (float)x_.h[0] * linv; av_[1] = (float)x_.h[1] * linv; \
    av_[2] = (float)x_.h[2] * linv; av_[3] = (float)x_.h[3] * linv; \
    __builtin_nontemporal_store(av_, (f32x4*)(arow + (colb_ >> 1))); }

__global__ __launch_bounds__(512, 4) void attn_main_k(
        const _Float16* __restrict__ qh, const _Float16* __restrict__ kh,
        const _Float16* __restrict__ vtp, const unsigned long long* __restrict__ pm,
        float* __restrict__ outp, float* __restrict__ attnp) {
    extern __shared__ char smem[];

    int bid = blockIdx.x;
    int lin = (bid & 7) * (NBLK / 8) + (bid >> 3);   // XCD swizzle, bijective
    int b  = lin >> 7;
    int q0 = (lin & 127) * ROWS;

    int t = threadIdx.x;
    int w = t >> 6, l = t & 63;
    int l15 = l & 15, lg = l >> 4;
    int sw = (l15 & 7) << 4;

    // Q as B-fragment: col = lane&15 = query, k = (lane>>4)*8 + j (+32 second half)
    const _Float16* qb = qh + ((size_t)(b * NN + q0 + l15) * ND) + lg * 8;
    half8 qf0 = *(const half8*)(qb);
    half8 qf1 = *(const half8*)(qb + 32);
    unsigned long long pmask = pm[((size_t)(b * NN + q0 + l15) * 8 + w) * 4 + lg];

    const _Float16* kp = kh + (size_t)b * NN * ND + (size_t)(w * 16 + l15) * ND + lg * 8;
    char* srow = smem + l15 * 4096;
    float* part = (float*)(smem + LDS_PART);

    // pin q/pm into registers so the compiler's own waitcnts land HERE,
    // then zero the vmcnt baseline: from now on only asm loads are outstanding.
    PIN(qf0); PIN(qf1); PIN(pmask);
    WAITV(0);

    // ---- Phase 1: fused QK^T + maskbits + exp + rowsum; TRUE depth-2 dbuf ----
    uint4 KA0a, KA0b, KA1a, KA1b, KA2a, KA2b, KA3a, KA3b;
    uint4 KB0a, KB0b, KB1a, KB1b, KB2a, KB2b, KB3a, KB3b;
    float rsum = 0.f;
    ISSUEK(KA, 0);
    ISSUEK(KB, 4);
    WAITV(8);          // KA ready, KB in flight
    CMP4(KA, 0);
    ISSUEK(KA, 8);
    WAITV(8);          // KB ready, KA8 in flight
    CMP4(KB, 1);
    ISSUEK(KB, 12);
    WAITV(8);          // KA8 ready, KB12 in flight
    CMP4(KA, 2);
    WAITV(0);          // KB12 ready
    CMP4(KB, 3);

    rsum += __shfl_xor(rsum, 16);
    rsum += __shfl_xor(rsum, 32);
    if (l < 16) part[w * 16 + l] = rsum;
    LBAR();                           // LDS-ordering only

    // ---- Phase 2: PV (kseg split) + out store; TRUE depth-2 dbuf ----
    {
        int ct = w & 3, kseg = w >> 2;
        const _Float16* vp = vtp + (size_t)(b * ND + ct * 16 + l15) * NN + lg * 8;
        char* pbase = smem + l15 * 4096;
        f32x4 o = {0.f, 0.f, 0.f, 0.f};
        uint4 V0, V1, V2, V3, V4, V5, V6, V7;
        uint4 W0, W1, W2, W3, W4, W5, W6, W7;
        ISSUEV(V, 0);
        ISSUEV(W, 8);
        WAITV(8);      // V ready, W in flight
        PV8(V, 0);
        ISSUEV(V, 16);
        WAITV(8);      // W ready, V16 in flight
        PV8(W, 8);
        ISSUEV(W, 24);
        WAITV(8);      // V16 ready, W24 in flight
        PV8(V, 16);
        WAITV(0);      // W24 ready
        PV8(W, 24);

        if (kseg) *(f32x4*)(smem + LDS_AUX + ((size_t)((w - 4) * 64 + l)) * 16) = o;
        LBAR();                       // LDS-ordering only (aux visible)
        if (!kseg) {
            f32x4 o2 = *(const f32x4*)(smem + LDS_AUX + ((size_t)(w * 64 + l)) * 16);
            o += o2;
            float* ob = outp + ((size_t)(b * NN + q0 + lg * 4)) * ND + ct * 16 + l15;
            #pragma unroll
            for (int rr = 0; rr < 4; ++rr) {
                int qr = lg * 4 + rr;
                float s8 = 0.f;
                #pragma unroll
                for (int pw = 0; pw < 8; ++pw) s8 += part[pw * 16 + qr];
                ob[(size_t)rr * ND] = o[rr] / (s8 + 1e-37f);   // plain store
            }
        }
    }

    // ---- Phase 3 (LAST): normalize + attn f32 store, all 8 waves ----
    // No trailing barrier: stores drain while the next block computes.
    {
        int r = t >> 5, g = t & 31;          // 2 rows/wave, 32 threads/row
        float su = 0.f;
        #pragma unroll
        for (int pw = 0; pw < 8; ++pw) su += part[pw * 16 + r];
        float linv = 1.0f / (su + 1e-37f);   // all-masked row -> attn = 0 (no NaN)
        char* s2 = smem + r * 4096;
        int sw2 = (r & 7) << 4;
        float* arow = attnp + ((size_t)(b * NN + q0 + r)) * NN;
        NRM(0)  NRM(1)  NRM(2)  NRM(3)
        NRM(4)  NRM(5)  NRM(6)  NRM(7)
        NRM(8)  NRM(9)  NRM(10) NRM(11)
        NRM(12) NRM(13) NRM(14) NRM(15)
    }
}

extern "C" void kernel_launch(void* const* d_in, const int* in_sizes, int n_in,
                              void* d_out, int out_size, void* d_ws, size_t ws_size,
                              hipStream_t stream) {
    const float* q = (const float*)d_in[0];
    const float* k = (const float*)d_in[1];
    const float* v = (const float*)d_in[2];
    const int* mask = (const int*)d_in[3];
    float* outp  = (float*)d_out;
    float* attnp = outp + (size_t)NB * NN * ND;

    // ws: qh 8MB | kh 8MB | vt 8MB | pm 16.8MB
    _Float16* qh = (_Float16*)d_ws;
    _Float16* kh = qh + (size_t)NB * NN * ND;
    _Float16* vth = kh + (size_t)NB * NN * ND;
    unsigned long long* pm = (unsigned long long*)(vth + (size_t)NB * NN * ND);

    cvt_f32_f16_k<<<2048, 256, 0, stream>>>(q, qh);
    cvt_f32_f16_k<<<2048, 256, 0, stream>>>(k, kh);
    transpose_v_k<<<1024, 256, 0, stream>>>(v, vth);
    mask_pack_k<<<8192, 256, 0, stream>>>(mask, pm);
    attn_main_k<<<NBLK, 512, LDS_TOTAL, stream>>>(qh, kh, vth, pm, outp, attnp);
}